// Round 1
// baseline (568.445 us; speedup 1.0000x reference)
//
#include <hip/hip_runtime.h>
#include <math.h>

#define HID 64
#define IND 3
#define DT 0.1f
#define MIN_TAU 0.1f
#define TAU_SCALE 9.9f   // MAX_TAU - MIN_TAU

__device__ __forceinline__ float fast_rcp(float x) {
    return __builtin_amdgcn_rcpf(x);
}

__device__ __forceinline__ float fast_tanh(float x) {
    // tanh(x) = 1 - 2/(exp(2x)+1); saturates correctly at +/-inf exp
    float e = __expf(2.f * x);
    return fmaf(-2.f, fast_rcp(e + 1.f), 1.f);
}

__global__ __launch_bounds__(256) void liquid_cell_kernel(
    const float* __restrict__ h, const float* __restrict__ u,
    const float* __restrict__ W_h, const float* __restrict__ U_h,
    const float* __restrict__ b_h,
    const float* __restrict__ W_tau, const float* __restrict__ U_tau,
    const float* __restrict__ b_tau,
    const float* __restrict__ W_out, const float* __restrict__ b_out,
    float* __restrict__ h_out, float* __restrict__ v_out, int total)
{
    int p = blockIdx.x * blockDim.x + threadIdx.x;
    if (p >= total) return;

    const size_t base = (size_t)p * HID;

    // Stage this position's h row into registers (compile-time indexed only).
    float hreg[HID];
    const float4* h4 = reinterpret_cast<const float4*>(h + base);
#pragma unroll
    for (int j = 0; j < HID / 4; ++j) {
        float4 t = h4[j];
        hreg[4 * j + 0] = t.x;
        hreg[4 * j + 1] = t.y;
        hreg[4 * j + 2] = t.z;
        hreg[4 * j + 3] = t.w;
    }

    const size_t ub = (size_t)p * IND;
    float u0 = u[ub + 0], u1 = u[ub + 1], u2 = u[ub + 2];

    float va0 = 0.f, va1 = 0.f, va2 = 0.f;

    float4* ho4 = reinterpret_cast<float4*>(h_out + base);

    for (int k4 = 0; k4 < HID / 4; ++k4) {
        float hn[4];
#pragma unroll
        for (int kk = 0; kk < 4; ++kk) {
            const int k = k4 * 4 + kk;   // wave-uniform
            // bias + input-drive terms (all weight reads are wave-uniform -> s_load)
            float at = b_tau[k];
            at = fmaf(u0, U_tau[k * IND + 0], at);
            at = fmaf(u1, U_tau[k * IND + 1], at);
            at = fmaf(u2, U_tau[k * IND + 2], at);
            float ap = b_h[k];
            ap = fmaf(u0, U_h[k * IND + 0], ap);
            ap = fmaf(u1, U_h[k * IND + 1], ap);
            ap = fmaf(u2, U_h[k * IND + 2], ap);

            const float* __restrict__ wt = W_tau + k * HID;
            const float* __restrict__ wh = W_h + k * HID;
#pragma unroll
            for (int j = 0; j < HID; ++j) {
                at = fmaf(hreg[j], wt[j], at);
                ap = fmaf(hreg[j], wh[j], ap);
            }

            // tau = MIN_TAU + softplus(at) * (MAX_TAU - MIN_TAU)
            float sp = fmaxf(at, 0.f) + __logf(1.f + __expf(-fabsf(at)));
            float tau = fmaf(sp, TAU_SCALE, MIN_TAU);

            // f_h = sigmoid(ap)
            float f = fast_rcp(1.f + __expf(-ap));

            // h_new = h + DT * (-h/tau + f)
            float hk = h[base + k];              // L1/L2 hit; avoids runtime reg-index
            float hnew = fmaf(DT, f - hk * fast_rcp(tau), hk);
            hn[kk] = hnew;

            va0 = fmaf(hnew, W_out[0 * HID + k], va0);
            va1 = fmaf(hnew, W_out[1 * HID + k], va1);
            va2 = fmaf(hnew, W_out[2 * HID + k], va2);
        }
        float4 hv = make_float4(hn[0], hn[1], hn[2], hn[3]);
        ho4[k4] = hv;
    }

    v_out[(size_t)p * 3 + 0] = fast_tanh(va0 + b_out[0]);
    v_out[(size_t)p * 3 + 1] = fast_tanh(va1 + b_out[1]);
    v_out[(size_t)p * 3 + 2] = fast_tanh(va2 + b_out[2]);
}

extern "C" void kernel_launch(void* const* d_in, const int* in_sizes, int n_in,
                              void* d_out, int out_size, void* d_ws, size_t ws_size,
                              hipStream_t stream) {
    const float* h     = (const float*)d_in[0];
    const float* u     = (const float*)d_in[1];
    const float* W_h   = (const float*)d_in[2];
    const float* U_h   = (const float*)d_in[3];
    const float* b_h   = (const float*)d_in[4];
    const float* W_tau = (const float*)d_in[5];
    const float* U_tau = (const float*)d_in[6];
    const float* b_tau = (const float*)d_in[7];
    const float* W_out = (const float*)d_in[8];
    const float* b_out = (const float*)d_in[9];

    const int total = in_sizes[0] / HID;   // B * N positions
    float* h_out = (float*)d_out;
    float* v_out = h_out + (size_t)total * HID;

    const int block = 256;
    const int grid = (total + block - 1) / block;
    liquid_cell_kernel<<<grid, block, 0, stream>>>(
        h, u, W_h, U_h, b_h, W_tau, U_tau, b_tau, W_out, b_out,
        h_out, v_out, total);
}

// Round 2
// 366.623 us; speedup vs baseline: 1.5505x; 1.5505x over previous
//
#include <hip/hip_runtime.h>
#include <hip/hip_bf16.h>
#include <math.h>

#define HID 64
#define DT 0.1f
#define MIN_TAU 0.1f
#define TAU_SCALE 9.9f   // MAX_TAU - MIN_TAU

// Wcat row: [W(64) | U(3) | b(1) | 0-pad(28)] = 96 cols, padded to 104 bf16
// -> row stride 208 B (16B-aligned for ds_read_b128, word-step 52 -> ~2-way banks = free)
#define WSTRIDE 104
#define KAUG 96           // 3 K-steps of 32

typedef __attribute__((ext_vector_type(8))) short bf16x8;
typedef __attribute__((ext_vector_type(4))) float f32x4;

__device__ __forceinline__ short f2bf(float f) {
    union { __hip_bfloat16 b; short s; } c;
    c.b = __float2bfloat16(f);
    return c.s;
}
__device__ __forceinline__ float fast_rcp(float x) { return __builtin_amdgcn_rcpf(x); }
__device__ __forceinline__ float fast_tanh(float x) {
    float e = __expf(2.f * x);
    return fmaf(-2.f, fast_rcp(e + 1.f), 1.f);
}

// Block = 256 threads = 4 waves; each wave owns 32 positions (2 M-tiles of 16).
// GEMM per wave: M=32, N=128 (kout2: 0..63 = tau_raw, 64..127 = pre), K=96.
__global__ __launch_bounds__(256, 2) void liquid_mfma_kernel(
    const float* __restrict__ h, const float* __restrict__ u,
    const float* __restrict__ W_h, const float* __restrict__ U_h,
    const float* __restrict__ b_h,
    const float* __restrict__ W_tau, const float* __restrict__ U_tau,
    const float* __restrict__ b_tau,
    const float* __restrict__ W_out, const float* __restrict__ b_out,
    float* __restrict__ h_out, float* __restrict__ v_out, long long total)
{
    __shared__ short wlds[128 * WSTRIDE];

    const int tid = threadIdx.x;

    // ---- stage augmented weights (bf16) into LDS: rows 0..63 tau, 64..127 h ----
    for (int idx = tid; idx < 128 * WSTRIDE; idx += 256) {
        const int row = idx / WSTRIDE;
        const int c = idx - row * WSTRIDE;
        const int r = row & 63;
        float val = 0.f;
        if (row < 64) {
            if (c < 64)       val = W_tau[r * 64 + c];
            else if (c < 67)  val = U_tau[r * 3 + (c - 64)];
            else if (c == 67) val = b_tau[r];
        } else {
            if (c < 64)       val = W_h[r * 64 + c];
            else if (c < 67)  val = U_h[r * 3 + (c - 64)];
            else if (c == 67) val = b_h[r];
        }
        wlds[idx] = f2bf(val);
    }

    const int lane = tid & 63;
    const int col  = lane & 15;   // own-dim index (M for A-frag/D-col... see layout notes)
    const int quad = lane >> 4;   // k-octet selector
    const int wid  = tid >> 6;

    // per-lane W_out / b_out (k = nt*16 + col)
    float wo[3][4];
#pragma unroll
    for (int o = 0; o < 3; ++o)
#pragma unroll
        for (int nt = 0; nt < 4; ++nt)
            wo[o][nt] = W_out[o * 64 + nt * 16 + col];
    const float bo0 = b_out[0], bo1 = b_out[1], bo2 = b_out[2];

    __syncthreads();

    const long long p0 = (long long)blockIdx.x * 128 + wid * 32;
    if (p0 + 32 > total) return;   // exact for this shape (total % 128 == 0)

    f32x4 acc[2][8];
#pragma unroll
    for (int mt = 0; mt < 2; ++mt)
#pragma unroll
        for (int nt = 0; nt < 8; ++nt)
            acc[mt][nt] = (f32x4){0.f, 0.f, 0.f, 0.f};

#pragma unroll
    for (int ks = 0; ks < 3; ++ks) {
        // A fragments: lane holds X[p = p0+mt*16+col, j = ks*32 + quad*8 + e]
        bf16x8 af[2];
#pragma unroll
        for (int mt = 0; mt < 2; ++mt) {
            const long long p = p0 + mt * 16 + col;
            if (ks < 2) {
                const float* hp = h + p * 64 + ks * 32 + quad * 8;
                const float4 x0 = *(const float4*)hp;
                const float4 x1 = *(const float4*)(hp + 4);
                bf16x8 a;
                a[0] = f2bf(x0.x); a[1] = f2bf(x0.y); a[2] = f2bf(x0.z); a[3] = f2bf(x0.w);
                a[4] = f2bf(x1.x); a[5] = f2bf(x1.y); a[6] = f2bf(x1.z); a[7] = f2bf(x1.w);
                af[mt] = a;
            } else {
                // augmented K-step: j=64..66 -> u, j=67 -> 1.0 (bias), rest 0
                bf16x8 a = (bf16x8)(short)0;
                if (quad == 0) {
                    const float* up = u + p * 3;
                    a[0] = f2bf(up[0]); a[1] = f2bf(up[1]); a[2] = f2bf(up[2]);
                    a[3] = f2bf(1.0f);
                }
                af[mt] = a;
            }
        }
        // B fragments from LDS: lane holds Wcat[n = nt*16+col][j = ks*32 + quad*8 + e]
#pragma unroll
        for (int nt = 0; nt < 8; ++nt) {
            const bf16x8 bfrag =
                *(const bf16x8*)&wlds[(nt * 16 + col) * WSTRIDE + ks * 32 + quad * 8];
#pragma unroll
            for (int mt = 0; mt < 2; ++mt)
                acc[mt][nt] = __builtin_amdgcn_mfma_f32_16x16x32_bf16(
                    af[mt], bfrag, acc[mt][nt], 0, 0, 0);
        }
    }

    // ---- epilogue: D[p = mt*16 + quad*4 + r, k = nt*16 + col] ----
#pragma unroll
    for (int mt = 0; mt < 2; ++mt) {
#pragma unroll
        for (int r = 0; r < 4; ++r) {
            const long long p = p0 + mt * 16 + quad * 4 + r;
            float pv0 = 0.f, pv1 = 0.f, pv2 = 0.f;
#pragma unroll
            for (int ntk = 0; ntk < 4; ++ntk) {
                const float at = acc[mt][ntk][r];       // tau_raw
                const float ap = acc[mt][ntk + 4][r];   // pre
                const float sp = fmaxf(at, 0.f) + __logf(1.f + __expf(-fabsf(at)));
                const float tau = fmaf(sp, TAU_SCALE, MIN_TAU);
                const float f = fast_rcp(1.f + __expf(-ap));
                const float hk = h[p * 64 + ntk * 16 + col];   // fp32 re-read (L2-hot)
                const float hnew = fmaf(DT, f - hk * fast_rcp(tau), hk);
                h_out[p * 64 + ntk * 16 + col] = hnew;         // 4x64B coalesced groups
                pv0 = fmaf(hnew, wo[0][ntk], pv0);
                pv1 = fmaf(hnew, wo[1][ntk], pv1);
                pv2 = fmaf(hnew, wo[2][ntk], pv2);
            }
            // reduce over k: across the 16 lanes of this quad
#pragma unroll
            for (int s = 1; s < 16; s <<= 1) {
                pv0 += __shfl_xor(pv0, s, 64);
                pv1 += __shfl_xor(pv1, s, 64);
                pv2 += __shfl_xor(pv2, s, 64);
            }
            if (col == 0) {
                v_out[p * 3 + 0] = fast_tanh(pv0 + bo0);
                v_out[p * 3 + 1] = fast_tanh(pv1 + bo1);
                v_out[p * 3 + 2] = fast_tanh(pv2 + bo2);
            }
        }
    }
}

extern "C" void kernel_launch(void* const* d_in, const int* in_sizes, int n_in,
                              void* d_out, int out_size, void* d_ws, size_t ws_size,
                              hipStream_t stream) {
    const float* h     = (const float*)d_in[0];
    const float* u     = (const float*)d_in[1];
    const float* W_h   = (const float*)d_in[2];
    const float* U_h   = (const float*)d_in[3];
    const float* b_h   = (const float*)d_in[4];
    const float* W_tau = (const float*)d_in[5];
    const float* U_tau = (const float*)d_in[6];
    const float* b_tau = (const float*)d_in[7];
    const float* W_out = (const float*)d_in[8];
    const float* b_out = (const float*)d_in[9];

    const long long total = in_sizes[0] / HID;   // B*N positions (1048576, %128==0)
    float* h_out = (float*)d_out;
    float* v_out = h_out + (size_t)total * HID;

    const int grid = (int)((total + 127) / 128);
    liquid_mfma_kernel<<<grid, 256, 0, stream>>>(
        h, u, W_h, U_h, b_h, W_tau, U_tau, b_tau, W_out, b_out,
        h_out, v_out, total);
}

// Round 3
// 199.667 us; speedup vs baseline: 2.8470x; 1.8362x over previous
//
#include <hip/hip_runtime.h>
#include <hip/hip_bf16.h>
#include <math.h>

#define HID 64
#define DT 0.1f
#define MIN_TAU 0.1f
#define TAU_SCALE 9.9f   // MAX_TAU - MIN_TAU

// Augmented weight row: [W(64) | U(3) | b(1) | 0-pad] = 68 used, padded to 104 bf16
// (208 B row stride, 16B-aligned; b128 reads at 52-word stride are phase-conflict-free)
#define WSTRIDE 104
#define WROWS   128
#define WELEMS  (WROWS * WSTRIDE)   // 13312 bf16 = 26624 B

typedef __attribute__((ext_vector_type(8))) short bf16x8;
typedef __attribute__((ext_vector_type(4))) float f32x4;

__device__ __forceinline__ short f2bf(float f) {
    union { __hip_bfloat16 b; short s; } c;
    c.b = __float2bfloat16(f);
    return c.s;
}
__device__ __forceinline__ float fast_rcp(float x) { return __builtin_amdgcn_rcpf(x); }
__device__ __forceinline__ float fast_tanh(float x) {
    float e = __expf(2.f * x);
    return fmaf(-2.f, fast_rcp(e + 1.f), 1.f);
}

// ---- kernel 0: convert + pack augmented weights into d_ws (runs once per launch) ----
__global__ __launch_bounds__(256) void prep_weights(
    const float* __restrict__ W_tau, const float* __restrict__ U_tau,
    const float* __restrict__ b_tau,
    const float* __restrict__ W_h, const float* __restrict__ U_h,
    const float* __restrict__ b_h,
    short* __restrict__ wbf)
{
    const int idx = blockIdx.x * 256 + threadIdx.x;
    if (idx >= WELEMS) return;
    const int row = idx / WSTRIDE;
    const int c = idx - row * WSTRIDE;
    const int r = row & 63;
    float val = 0.f;
    if (row < 64) {
        if (c < 64)       val = W_tau[r * 64 + c];
        else if (c < 67)  val = U_tau[r * 3 + (c - 64)];
        else if (c == 67) val = b_tau[r];
    } else {
        if (c < 64)       val = W_h[r * 64 + c];
        else if (c < 67)  val = U_h[r * 3 + (c - 64)];
        else if (c == 67) val = b_h[r];
    }
    wbf[idx] = f2bf(val);
}

// ---- main kernel: 256 thr = 4 waves; wave handles 16 positions (M=16), tile = 64 pos ----
// GEMM per wave-tile: M=16, N=128 (cols 0..63 tau_raw, 64..127 pre), K=96 (h|u|1)
__global__ __launch_bounds__(256) void liquid_mfma_kernel(
    const float* __restrict__ h, const float* __restrict__ u,
    const short* __restrict__ wbf,
    const float* __restrict__ W_out, const float* __restrict__ b_out,
    float* __restrict__ h_out, float* __restrict__ v_out, long long ntiles)
{
    __shared__ short wlds[WELEMS];

    const int tid = threadIdx.x;
    {   // fast stage: 26624 B as 1664 uint4 (b128 writes, conflict-free)
        const uint4* s = (const uint4*)wbf;
        uint4* d = (uint4*)wlds;
        for (int i = tid; i < WELEMS / 8; i += 256) d[i] = s[i];
    }

    const int lane = tid & 63;
    const int col  = lane & 15;
    const int quad = lane >> 4;
    const int wid  = tid >> 6;

    float wo[3][4];
#pragma unroll
    for (int o = 0; o < 3; ++o)
#pragma unroll
        for (int nt = 0; nt < 4; ++nt)
            wo[o][nt] = W_out[o * 64 + nt * 16 + col];
    const float bo0 = b_out[0], bo1 = b_out[1], bo2 = b_out[2];

    __syncthreads();   // LDS is read-only below: no barriers in the tile loop

    const long long tstep = gridDim.x;
    long long t = blockIdx.x;

    // prefetch regs for A (16 pos x 64 k per wave -> 4 float4/lane)
    float4 pf0, pf1, pf2, pf3;

#define LOADA(TT)                                                              \
    do {                                                                       \
        const long long q0_ = (TT) * 64 + wid * 16;                            \
        const float* hp_ = h + (q0_ + col) * 64 + quad * 8;                    \
        pf0 = *(const float4*)hp_;                                             \
        pf1 = *(const float4*)(hp_ + 4);                                       \
        pf2 = *(const float4*)(hp_ + 32);                                      \
        pf3 = *(const float4*)(hp_ + 36);                                      \
    } while (0)

    if (t < ntiles) LOADA(t);

    for (; t < ntiles; t += tstep) {
        const long long q0 = t * 64 + wid * 16;

        // ---- convert prefetched A to bf16 fragments (frees pf for next tile) ----
        bf16x8 af0, af1;
        af0[0] = f2bf(pf0.x); af0[1] = f2bf(pf0.y); af0[2] = f2bf(pf0.z); af0[3] = f2bf(pf0.w);
        af0[4] = f2bf(pf1.x); af0[5] = f2bf(pf1.y); af0[6] = f2bf(pf1.z); af0[7] = f2bf(pf1.w);
        af1[0] = f2bf(pf2.x); af1[1] = f2bf(pf2.y); af1[2] = f2bf(pf2.z); af1[3] = f2bf(pf2.w);
        af1[4] = f2bf(pf3.x); af1[5] = f2bf(pf3.y); af1[6] = f2bf(pf3.z); af1[7] = f2bf(pf3.w);

        // augmented K-step fragment: j=64..66 -> u, j=67 -> 1.0
        bf16x8 af2 = (bf16x8)(short)0;
        if (quad == 0) {
            const float* up = u + (q0 + col) * 3;
            af2[0] = f2bf(up[0]); af2[1] = f2bf(up[1]); af2[2] = f2bf(up[2]);
            af2[3] = f2bf(1.0f);
        }

        // ---- issue next tile's A loads early (hide under MFMA + epilogue) ----
        const long long tn = t + tstep;
        if (tn < ntiles) LOADA(tn);

        // ---- MFMA: acc[nt] over N=128, K=96 ----
        f32x4 acc[8];
#pragma unroll
        for (int nt = 0; nt < 8; ++nt) acc[nt] = (f32x4){0.f, 0.f, 0.f, 0.f};

#pragma unroll
        for (int nt = 0; nt < 8; ++nt) {
            const short* wb = &wlds[(nt * 16 + col) * WSTRIDE + quad * 8];
            acc[nt] = __builtin_amdgcn_mfma_f32_16x16x32_bf16(
                af0, *(const bf16x8*)wb, acc[nt], 0, 0, 0);
            acc[nt] = __builtin_amdgcn_mfma_f32_16x16x32_bf16(
                af1, *(const bf16x8*)(wb + 32), acc[nt], 0, 0, 0);
            acc[nt] = __builtin_amdgcn_mfma_f32_16x16x32_bf16(
                af2, *(const bf16x8*)(wb + 64), acc[nt], 0, 0, 0);
        }

        // ---- epilogue: D[p = quad*4 + r, k = ntk*16 + col] ----
#pragma unroll
        for (int r = 0; r < 4; ++r) {
            const long long p = q0 + quad * 4 + r;
            float pv0 = 0.f, pv1 = 0.f, pv2 = 0.f;
#pragma unroll
            for (int ntk = 0; ntk < 4; ++ntk) {
                const float at = acc[ntk][r];       // tau_raw
                const float ap = acc[ntk + 4][r];   // pre
                const float sp = fmaxf(at, 0.f) + __logf(1.f + __expf(-fabsf(at)));
                const float tau = fmaf(sp, TAU_SCALE, MIN_TAU);
                const float f = fast_rcp(1.f + __expf(-ap));
                const float hk = h[p * 64 + ntk * 16 + col];   // L1/L2-hot re-read
                const float hnew = fmaf(DT, f - hk * fast_rcp(tau), hk);
                h_out[p * 64 + ntk * 16 + col] = hnew;         // 64B-coalesced groups
                pv0 = fmaf(hnew, wo[0][ntk], pv0);
                pv1 = fmaf(hnew, wo[1][ntk], pv1);
                pv2 = fmaf(hnew, wo[2][ntk], pv2);
            }
#pragma unroll
            for (int s = 1; s < 16; s <<= 1) {
                pv0 += __shfl_xor(pv0, s, 64);
                pv1 += __shfl_xor(pv1, s, 64);
                pv2 += __shfl_xor(pv2, s, 64);
            }
            if (col == 0) {
                v_out[p * 3 + 0] = fast_tanh(pv0 + bo0);
                v_out[p * 3 + 1] = fast_tanh(pv1 + bo1);
                v_out[p * 3 + 2] = fast_tanh(pv2 + bo2);
            }
        }
    }
#undef LOADA
}

extern "C" void kernel_launch(void* const* d_in, const int* in_sizes, int n_in,
                              void* d_out, int out_size, void* d_ws, size_t ws_size,
                              hipStream_t stream) {
    const float* h     = (const float*)d_in[0];
    const float* u     = (const float*)d_in[1];
    const float* W_h   = (const float*)d_in[2];
    const float* U_h   = (const float*)d_in[3];
    const float* b_h   = (const float*)d_in[4];
    const float* W_tau = (const float*)d_in[5];
    const float* U_tau = (const float*)d_in[6];
    const float* b_tau = (const float*)d_in[7];
    const float* W_out = (const float*)d_in[8];
    const float* b_out = (const float*)d_in[9];

    const long long total = in_sizes[0] / HID;   // B*N positions (1048576)
    float* h_out = (float*)d_out;
    float* v_out = h_out + (size_t)total * HID;

    short* wbf = (short*)d_ws;   // 26624 B of scratch

    prep_weights<<<(WELEMS + 255) / 256, 256, 0, stream>>>(
        W_tau, U_tau, b_tau, W_h, U_h, b_h, wbf);

    const long long ntiles = total / 64;   // 64 positions per block-tile
    const int grid = 1280;                 // ~5 blocks/CU, grid-stride over tiles
    liquid_mfma_kernel<<<grid, 256, 0, stream>>>(
        h, u, wbf, W_out, b_out, h_out, v_out, ntiles);
}